// Round 9
// baseline (332.418 us; speedup 1.0000x reference)
//
#include <hip/hip_runtime.h>
#include <hip/hip_bf16.h>
#include <cstdint>
#include <cstddef>

// MultiHeadAttention: B=4,S=2048,D=1024,H=16,DK=64, causal. fp32 in, fp32 out.
// Round 16:
//   - REVERT R15's pipelined GEMMs (proj_qkv8/gemm_out8 regressed: 1 block/CU
//     barrier-locked, coarse graft of 8-phase schedule; m232-OPEN quadrant).
//     proj_qkv (R13/R14, 74us) + gemm_out (R14) restored.
//   - flash v6: 32 q-rows/wave (two 16-row groups g=0,1) SHARING K/V LDS
//     fragment reads -> LDS bytes per MFMA halved (LDS pipe was ~2x MFMA
//     time: 8 waves x 16KB = 128KB/tile = ~1024cy vs ~515cy MFMA).
//     256 thr = 4 waves, q-tile 128, grid (64,8) = 2 blocks/CU kept for
//     cross-block barrier overlap (R15 lesson). Staging constants unchanged
//     (f(row+32)=f(row)); each thread stages 2 chunks (R8 pattern).
// Carried (verified): cvt_all; proj_qkv XCD-remap + warm-L2 staging; flash
// in-register softmax machinery (key-permuted swapped QK^T, T13, exp2).
// Fragment layouts (HW-verified): A/B 16x16x32 [m|n=lane&15][k=quad*8+j];
// C/D col=lane&15, row=quad*4+reg.

namespace {

constexpr int B  = 4;
constexpr int S  = 2048;
constexpr int D  = 1024;
constexpr int H  = 16;
constexpr int DK = 64;
constexpr int M  = B * S;
constexpr float LOG2E     = 1.44269504088896f;
constexpr float QSCALE    = 0.125f * LOG2E;  // sm-scale folded with log2(e)
constexpr float NEG_BIG   = -1e30f;
constexpr float DEFER_THR = 8.0f;            // T13, log2 domain (p <= 2^8)

using bf16 = __hip_bfloat16;

typedef __attribute__((ext_vector_type(8))) __bf16 bf16x8;
typedef __attribute__((ext_vector_type(4))) float  f32x4;

__device__ __forceinline__ uint16_t f2bfu(float x) { // RNE fp32->bf16 bits
  uint32_t a = __builtin_bit_cast(uint32_t, x);
  return (uint16_t)((a + 0x7FFFu + ((a >> 16) & 1u)) >> 16);
}
__device__ __forceinline__ uint32_t pk2(float x, float y) {
  return (uint32_t)f2bfu(x) | ((uint32_t)f2bfu(y) << 16);
}
__device__ __forceinline__ float ex2(float x) { // 2^x
  float r; asm("v_exp_f32 %0, %1" : "=v"(r) : "v"(x)); return r;
}
__device__ __forceinline__ uint32_t cvtpk(float lo, float hi) { // {bf16(lo),bf16(hi)} RNE
  uint32_t r;
  asm("v_cvt_pk_bf16_f32 %0, %1, %2" : "=v"(r) : "v"(lo), "v"(hi));
  return r;
}
__device__ __forceinline__ float hmax4(f32x4 v) {
  return fmaxf(fmaxf(v[0], v[1]), fmaxf(v[2], v[3]));
}

// async 16B global -> LDS (wave-uniform LDS base + lane*16 implicit)
__device__ __forceinline__ void ldst16(const uint4* g, uint4* l) {
  __builtin_amdgcn_global_load_lds(
      (const __attribute__((address_space(1))) void*)g,
      (__attribute__((address_space(3))) void*)l, 16, 0, 0);
}

// XCD-bijective remap for 512-block (8x64) grids: orig = x + 8y.
// bx = (orig>>3)&7, by = (orig&7)*8 + (orig>>6). Blocks sharing an A
// row-panel (same by, all bx) are 8 consecutive same-XCD dispatches.
__device__ __forceinline__ void xcd_remap(int& bx, int& by) {
  const int orig = blockIdx.x + (blockIdx.y << 3);
  bx = (orig >> 3) & 7;
  by = ((orig & 7) << 3) + (orig >> 6);
}

// ---------------------------------------------------------------------------
// cvt_all: all 7 fp32->bf16 conversions in one launch.
// ---------------------------------------------------------------------------
__global__ __launch_bounds__(256)
void cvt_all(const float* __restrict__ q, const float* __restrict__ k,
             const float* __restrict__ v, const float* __restrict__ wq,
             const float* __restrict__ wk, const float* __restrict__ wv,
             const float* __restrict__ wo, bf16* __restrict__ dq,
             bf16* __restrict__ dk, bf16* __restrict__ dv,
             bf16* __restrict__ dw)
{
  constexpr int N8IN = 1 << 20;            // qkv/8
  constexpr int N8W  = 1 << 17;            // D*D/8
  constexpr int T3   = 3 * N8IN;

  const int gi = blockIdx.x * 256 + threadIdx.x;
  const float* src; bf16* dst; int i;
  if (gi < T3) {
    const int z = gi >> 20; i = gi & (N8IN - 1);
    src = (z == 0) ? q : (z == 1) ? k : v;
    dst = (z == 0) ? dq : (z == 1) ? dk : dv;
  } else {
    const int j = gi - T3;
    const int z = j >> 17; i = j & (N8W - 1);
    src = (z == 0) ? wq : (z == 1) ? wk : (z == 2) ? wv : wo;
    dst = dw + ((size_t)z << 20);          // z * N8W * 8 elems
  }
  const float4 p = ((const float4*)src)[2 * i];
  const float4 r4 = ((const float4*)src)[2 * i + 1];
  uint4 r;
  r.x = pk2(p.x, p.y); r.y = pk2(p.z, p.w);
  r.z = pk2(r4.x, r4.y); r.w = pk2(r4.z, r4.w);
  ((uint4*)dst)[i] = r;
}

// ---------------------------------------------------------------------------
// fp32 -> bf16 bulk convert, up to 3 tensors per launch (fallback path only).
// ---------------------------------------------------------------------------
__global__ __launch_bounds__(256)
void cvt3(const float* __restrict__ a, const float* __restrict__ b,
          const float* __restrict__ c, bf16* __restrict__ x,
          bf16* __restrict__ y, bf16* __restrict__ z_, int n8)
{
  const int zz = blockIdx.y;
  const float* src = (zz == 0) ? a : (zz == 1) ? b : c;
  bf16*        dst = (zz == 0) ? x : (zz == 1) ? y : z_;
  const int i = blockIdx.x * 256 + threadIdx.x;
  if (i >= n8) return;
  const float4 p = ((const float4*)src)[2 * i];
  const float4 q = ((const float4*)src)[2 * i + 1];
  uint4 r;
  r.x = pk2(p.x, p.y); r.y = pk2(p.z, p.w);
  r.z = pk2(q.x, q.y); r.w = pk2(q.z, q.w);
  ((uint4*)dst)[i] = r;
}

// ---------------------------------------------------------------------------
// proj_qkv: the three input projections in one dispatch. blockIdx.z picks
// {Q,K,V}. A (bf16, pre-converted) and B (bf16 weights) both staged via
// global_load_lds. Single-buffer 32KB LDS, 2-barrier m97 loop, 4 blocks/CU.
// XCD-remapped within each z-slice.   [verified 74us, 49MB fetch]
// ---------------------------------------------------------------------------
__global__ __launch_bounds__(256, 4)
void proj_qkv(const bf16* __restrict__ Aq, const bf16* __restrict__ Ak,
              const bf16* __restrict__ Av, const bf16* __restrict__ Wall,
              const float* __restrict__ bq_, const float* __restrict__ bk_,
              const float* __restrict__ bv_, bf16* __restrict__ qo,
              bf16* __restrict__ ko, bf16* __restrict__ vto)
{
  __shared__ uint4 AsU[1024]; // 128 rows x 8 chunks (16KB)
  __shared__ uint4 BsU[1024];

  const int z = blockIdx.z;
  const bf16*  A    = (z == 0) ? Aq : (z == 1) ? Ak : Av;
  const bf16*  Wb   = Wall + (size_t)z * D * D;
  const float* bias = (z == 0) ? bq_ : (z == 1) ? bk_ : bv_;

  const int tid  = threadIdx.x;
  const int w    = tid >> 6;
  const int lane = tid & 63;
  const int lm   = lane & 15;
  const int quad = lane >> 4;
  const int wm   = (w >> 1) * 64;
  const int wn   = (w & 1) * 64;

  int bx, by; xcd_remap(bx, by);
  const int row0 = by * 128, col0 = bx * 128;
  constexpr int g8 = D >> 3; // 128 uint4 per row

  const uint4* Ag = (const uint4*)A + (size_t)row0 * g8;
  const uint4* Bg = (const uint4*)Wb + (size_t)col0 * g8;

  f32x4 acc[4][4] = {};

  for (int kt = 0; kt < D / 64; ++kt) {
    __syncthreads();
#pragma unroll
    for (int i = 0; i < 4; ++i) {
      const int chunk = i * 256 + w * 64 + lane; // 0..1023
      const int r = chunk >> 3, c = chunk & 7;
      ldst16(&Ag[(size_t)r * g8 + kt * 8 + c], &AsU[i * 256 + w * 64]);
      ldst16(&Bg[(size_t)r * g8 + kt * 8 + c], &BsU[i * 256 + w * 64]);
    }
    __syncthreads();
#pragma unroll
    for (int kk = 0; kk < 2; ++kk) {
      bf16x8 af[4], bfr[4];
#pragma unroll
      for (int tm = 0; tm < 4; ++tm)
        af[tm] = __builtin_bit_cast(bf16x8, AsU[(wm + tm * 16 + lm) * 8 + kk * 4 + quad]);
#pragma unroll
      for (int tn = 0; tn < 4; ++tn)
        bfr[tn] = __builtin_bit_cast(bf16x8, BsU[(wn + tn * 16 + lm) * 8 + kk * 4 + quad]);
#pragma unroll
      for (int tm = 0; tm < 4; ++tm)
#pragma unroll
        for (int tn = 0; tn < 4; ++tn)
          acc[tm][tn] = __builtin_amdgcn_mfma_f32_16x16x32_bf16(af[tm], bfr[tn], acc[tm][tn], 0, 0, 0);
    }
  }

  const float scale = (z == 0) ? QSCALE : 1.0f;
#pragma unroll
  for (int tm = 0; tm < 4; ++tm) {
#pragma unroll
    for (int tn = 0; tn < 4; ++tn) {
      const int col = col0 + wn + tn * 16 + lm;
      const float bv = bias[col];
      if (z == 2) {
        float vv[4];
#pragma unroll
        for (int r = 0; r < 4; ++r) vv[r] = acc[tm][tn][r] + bv;
        const int s0 = row0 + wm + tm * 16 + quad * 4;
        const int b_ = s0 >> 11, ss = s0 & (S - 1);
        const int h_ = col >> 6, dk = col & (DK - 1);
        uint2 st; st.x = pk2(vv[0], vv[1]); st.y = pk2(vv[2], vv[3]);
        *(uint2*)(vto + (((size_t)b_ * H + h_) * DK + dk) * S + ss) = st;
      } else {
        bf16* out = (z == 0) ? qo : ko;
#pragma unroll
        for (int r = 0; r < 4; ++r) {
          const int row = row0 + wm + tm * 16 + quad * 4 + r;
          const float v = (acc[tm][tn][r] + bv) * scale;
          const int b_ = row >> 11, s_ = row & (S - 1);
          const int h_ = col >> 6,  dk = col & (DK - 1);
          out[(((size_t)b_ * H + h_) * S + s_) * DK + dk] =
              __builtin_bit_cast(bf16, f2bfu(v));
        }
      }
    }
  }
}

// ---------------------------------------------------------------------------
// gemm_out: output projection. out = ctx@Wo^T + bo (fp32 [M,D] store).
// 512 thr = 8 waves (2Mx4N; wave owns 64x32 = 4x2 frags), 128x128 tile,
// BK=64, single-buffer 32KB LDS, XCD-remap. 16 waves/CU.   [R14]
// ---------------------------------------------------------------------------
__global__ __launch_bounds__(512)
void gemm_out(const bf16* __restrict__ A, const bf16* __restrict__ Wb,
              const float* __restrict__ bias, float* __restrict__ out)
{
  __shared__ uint4 AsU[1024]; // 128 rows x 8 chunks (16KB)
  __shared__ uint4 BsU[1024];

  const int tid  = threadIdx.x;
  const int w    = tid >> 6;          // 0..7
  const int lane = tid & 63;
  const int lm   = lane & 15;
  const int quad = lane >> 4;
  const int wm   = (w >> 2) * 64;     // 0 | 64
  const int wn   = (w & 3) * 32;      // 0 | 32 | 64 | 96

  int bx, by; xcd_remap(bx, by);
  const int row0 = by * 128, col0 = bx * 128;
  constexpr int g8 = D >> 3;

  const uint4* Ag = (const uint4*)A + (size_t)row0 * g8;
  const uint4* Bg = (const uint4*)Wb + (size_t)col0 * g8;

  f32x4 acc[4][2] = {};

  for (int kt = 0; kt < D / 64; ++kt) {
    __syncthreads();
#pragma unroll
    for (int i = 0; i < 2; ++i) {
      const int chunk = i * 512 + w * 64 + lane; // 0..1023
      const int r = chunk >> 3, c = chunk & 7;
      ldst16(&Ag[(size_t)r * g8 + kt * 8 + c], &AsU[i * 512 + w * 64]);
      ldst16(&Bg[(size_t)r * g8 + kt * 8 + c], &BsU[i * 512 + w * 64]);
    }
    __syncthreads();
#pragma unroll
    for (int kk = 0; kk < 2; ++kk) {
      bf16x8 af[4], bfr[2];
#pragma unroll
      for (int tm = 0; tm < 4; ++tm)
        af[tm] = __builtin_bit_cast(bf16x8, AsU[(wm + tm * 16 + lm) * 8 + kk * 4 + quad]);
#pragma unroll
      for (int tn = 0; tn < 2; ++tn)
        bfr[tn] = __builtin_bit_cast(bf16x8, BsU[(wn + tn * 16 + lm) * 8 + kk * 4 + quad]);
#pragma unroll
      for (int tm = 0; tm < 4; ++tm)
#pragma unroll
        for (int tn = 0; tn < 2; ++tn)
          acc[tm][tn] = __builtin_amdgcn_mfma_f32_16x16x32_bf16(af[tm], bfr[tn], acc[tm][tn], 0, 0, 0);
    }
  }

#pragma unroll
  for (int tm = 0; tm < 4; ++tm) {
#pragma unroll
    for (int tn = 0; tn < 2; ++tn) {
      const int col = col0 + wn + tn * 16 + lm;
      const float bv = bias[col];
#pragma unroll
      for (int r = 0; r < 4; ++r) {
        const int row = row0 + wm + tm * 16 + quad * 4 + r;
        out[(size_t)row * D + col] = acc[tm][tn][r] + bv;
      }
    }
  }
}

// ---------------------------------------------------------------------------
// gemm128 (fallback path only): dbuf 128x128, modes as before.
// ---------------------------------------------------------------------------
template <int MODE>
__global__ __launch_bounds__(256)
void gemm128(const bf16* __restrict__ A, const bf16* __restrict__ Wb,
             const float* __restrict__ bias, void* __restrict__ out,
             int N, int K, float scale)
{
  __shared__ uint4 AsU[2][1024];
  __shared__ uint4 BsU[2][1024];

  const int tid  = threadIdx.x;
  const int w    = tid >> 6;
  const int lane = tid & 63;
  const int lm   = lane & 15;
  const int quad = lane >> 4;
  const int wm   = (w >> 1) * 64;
  const int wn   = (w & 1) * 64;

  int bx, by; xcd_remap(bx, by);
  const int row0 = by * 128, col0 = bx * 128;
  const int g8 = K >> 3;

  const uint4* Ag = (const uint4*)A + (size_t)row0 * g8;
  const uint4* Bg = (const uint4*)Wb + (size_t)col0 * g8;

  f32x4 acc[4][4] = {};
  const int KT = K / 64;

#pragma unroll
  for (int i = 0; i < 4; ++i) {
    const int chunk = i * 256 + w * 64 + lane;
    const int r = chunk >> 3, c = chunk & 7;
    ldst16(&Ag[(size_t)r * g8 + c], &AsU[0][i * 256 + w * 64]);
    ldst16(&Bg[(size_t)r * g8 + c], &BsU[0][i * 256 + w * 64]);
  }

  int cur = 0;
  for (int kt = 0; kt < KT; ++kt) {
    __syncthreads();
    if (kt + 1 < KT) {
#pragma unroll
      for (int i = 0; i < 4; ++i) {
        const int chunk = i * 256 + w * 64 + lane;
        const int r = chunk >> 3, c = chunk & 7;
        ldst16(&Ag[(size_t)r * g8 + (kt + 1) * 8 + c], &AsU[cur ^ 1][i * 256 + w * 64]);
        ldst16(&Bg[(size_t)r * g8 + (kt + 1) * 8 + c], &BsU[cur ^ 1][i * 256 + w * 64]);
      }
    }
#pragma unroll
    for (int kk = 0; kk < 2; ++kk) {
      bf16x8 af[4], bfr[4];
#pragma unroll
      for (int tm = 0; tm < 4; ++tm)
        af[tm] = __builtin_bit_cast(bf16x8, AsU[cur][(wm + tm * 16 + lm) * 8 + kk * 4 + quad]);
#pragma unroll
      for (int tn = 0; tn < 4; ++tn)
        bfr[tn] = __builtin_bit_cast(bf16x8, BsU[cur][(wn + tn * 16 + lm) * 8 + kk * 4 + quad]);
#pragma unroll
      for (int tm = 0; tm < 4; ++tm)
#pragma unroll
        for (int tn = 0; tn < 4; ++tn)
          acc[tm][tn] = __builtin_amdgcn_mfma_f32_16x16x32_bf16(af[tm], bfr[tn], acc[tm][tn], 0, 0, 0);
    }
    cur ^= 1;
  }

#pragma unroll
  for (int tm = 0; tm < 4; ++tm) {
#pragma unroll
    for (int tn = 0; tn < 4; ++tn) {
      const int col = col0 + wn + tn * 16 + lm;
      const float bv = bias[col];
      if (MODE == 2) {
        float vv[4];
#pragma unroll
        for (int r = 0; r < 4; ++r) vv[r] = (acc[tm][tn][r] + bv) * scale;
        const int s0 = row0 + wm + tm * 16 + quad * 4;
        const int b_ = s0 >> 11, ss = s0 & (S - 1);
        const int h_ = col >> 6, dk = col & (DK - 1);
        uint2 st; st.x = pk2(vv[0], vv[1]); st.y = pk2(vv[2], vv[3]);
        *(uint2*)((bf16*)out + (((size_t)b_ * H + h_) * DK + dk) * S + ss) = st;
      } else {
#pragma unroll
        for (int r = 0; r < 4; ++r) {
          const int row = row0 + wm + tm * 16 + quad * 4 + r;
          const float v = (acc[tm][tn][r] + bv) * scale;
          if (MODE == 0) {
            ((float*)out)[(size_t)row * N + col] = v;
          } else {
            const int b_ = row >> 11, s_ = row & (S - 1);
            const int h_ = col >> 6,  dk = col & (DK - 1);
            ((bf16*)out)[(((size_t)b_ * H + h_) * S + s_) * DK + dk] =
                __builtin_bit_cast(bf16, f2bfu(v));
          }
        }
      }
    }
  }
}

// ---------------------------------------------------------------------------
// flash v6 (causal MFMA, in-register softmax, shared K/V reads).
// Q,K: [B*H,S,DK] bf16 (Q pre-scaled by 0.125*log2e); Vt: [B*H,DK,S] bf16.
// Grid (B*H, 8), 256 thr = 4 waves; wave w owns 32 q-rows: qb = q0 + w*32,
// groups g=0,1 at qb + g*16 + [0,16). K/V fragment reads are made ONCE per
// tile and feed both groups' MFMAs (halves LDS bytes per MFMA).
// Swapped QK^T key permutation (per g): sc[g][tn][r] =
// S[k0 + 32(tn>>1)+8*quad+4(tn&1)+r][qb+g*16+lm]; PV A-frags packed fully
// in-register (8 cvt_pk per g), no LDS round-trip.
// LDS swizzle f(row)=(row&7)^(((row>>3)&1)<<2); f(row+32)=f(row) so the
// per-thread source-chunk constant covers both staged halves.
// g=0 (lower rows) goes causally inactive first: guarded by wave-uniform a0.
// ---------------------------------------------------------------------------
__global__ __launch_bounds__(256)
void flash_mfma(const bf16* __restrict__ Q, const bf16* __restrict__ K,
                const bf16* __restrict__ Vt, bf16* __restrict__ ctx)
{
  __shared__ uint4 KsU[2][512];          // 2 x (64 keys x 64 dk) (16KB)
  __shared__ uint4 VtU[2][512];          // 2 x (64 d x 64 keys)  (16KB)
  __shared__ uint16_t Os[128 * 72];      // epilogue O staging (18KB)

  const int tid  = threadIdx.x;
  const int w    = tid >> 6;             // 0..3
  const int lane = tid & 63;
  const int lm   = lane & 15;
  const int quad = lane >> 4;
  const int bh   = blockIdx.x;           // 0..63
  const int pr   = blockIdx.y;           // 0..7
  const size_t base = (size_t)bh * S * DK;

  const uint4* Kg0 = (const uint4*)(K + base);
  const uint4* Vg0 = (const uint4*)(Vt + (size_t)bh * DK * S);

  // staging rows rr and 32+rr; f(row)=(row&7)^(((row>>3)&1)<<2), f(r+32)=f(r)
  const int rr  = tid >> 3;                                     // 0..31
  const int csw = (tid & 7) ^ ((tid >> 3) & 7) ^ (((tid >> 6) & 1) << 2);
  const int fv  = (lm & 7) ^ (((lm >> 3) & 1) << 2);            // V read rows
  const int r0  = ((lm >> 2) << 3) | (lm & 3);                  // K perm base

  const int b_ = bh >> 4, h_ = bh & (H - 1);

  for (int pass = 0; pass < 2; ++pass) {
    const int qi = pass ? (15 - pr) : pr;
    const int q0 = qi * 128;
    const int qb = q0 + w * 32;          // wave rows: qb + g*16 + [0,16)

    bf16x8 qf[2][2];
#pragma unroll
    for (int g = 0; g < 2; ++g) {
      const bf16* qrow = Q + base + (size_t)(qb + g * 16 + lm) * DK;
      qf[g][0] = __builtin_bit_cast(bf16x8, *(const uint4*)(qrow + quad * 8));
      qf[g][1] = __builtin_bit_cast(bf16x8, *(const uint4*)(qrow + 32 + quad * 8));
    }

    f32x4 o[2][4] = {};
    float m_i[2] = {NEG_BIG, NEG_BIG};
    float l_i[2] = {0.f, 0.f};

    const int nt = 2 * qi + 2;

    // prologue: stage tile 0 into buf 0 (2 K-chunks + 2 V-chunks per thread)
    ldst16(&Kg0[(size_t)rr * 8 + csw],               &KsU[0][w * 64]);
    ldst16(&Kg0[(size_t)(32 + rr) * 8 + csw],        &KsU[0][256 + w * 64]);
    ldst16(&Vg0[(size_t)rr * (S / 8) + csw],         &VtU[0][w * 64]);
    ldst16(&Vg0[(size_t)(32 + rr) * (S / 8) + csw],  &VtU[0][256 + w * 64]);

    int cur = 0;
    for (int t = 0; t < nt; ++t) {
      __syncthreads();
      if (t + 1 < nt) {
        const int k1 = (t + 1) * 64;
        ldst16(&Kg0[(size_t)(k1 + rr) * 8 + csw],               &KsU[cur ^ 1][w * 64]);
        ldst16(&Kg0[(size_t)(k1 + 32 + rr) * 8 + csw],          &KsU[cur ^ 1][256 + w * 64]);
        ldst16(&Vg0[(size_t)rr * (S / 8) + k1 / 8 + csw],       &VtU[cur ^ 1][w * 64]);
        ldst16(&Vg0[(size_t)(32 + rr) * (S / 8) + k1 / 8 + csw], &VtU[cur ^ 1][256 + w * 64]);
      }
      const int k0 = t * 64;
      if (k0 <= qb + 31) {               // g=1 active => tile entered
        const bool a0 = (k0 <= qb + 15); // g=0 (lower rows) still active?
        const uint4* Ks = KsU[cur];
        const uint4* Vs = VtU[cur];

        // QK^T — K fragments read ONCE, feed both groups
        f32x4 sc[2][4];
        __builtin_amdgcn_s_setprio(1);
#pragma unroll
        for (int tn = 0; tn < 4; ++tn) {
          const int row = r0 + ((tn & 1) << 2) + ((tn >> 1) << 5);
          const int fr  = (row & 7) ^ (((row >> 3) & 1) << 2);
          const int cb  = quad ^ fr;
          bf16x8 kb0 = __builtin_bit_cast(bf16x8, Ks[row * 8 + cb]);
          bf16x8 kb1 = __builtin_bit_cast(bf16x8, Ks[row * 8 + (cb ^ 4)]);
          sc[1][tn] = __builtin_amdgcn_mfma_f32_16x16x32_bf16(
                          kb0, qf[1][0], f32x4{0.f, 0.f, 0.f, 0.f}, 0, 0, 0);
          sc[1][tn] = __builtin_amdgcn_mfma_f32_16x16x32_bf16(kb1, qf[1][1], sc[1][tn], 0, 0, 0);
          if (a0) {
            sc[0][tn] = __builtin_amdgcn_mfma_f32_16x16x32_bf16(
                            kb0, qf[0][0], f32x4{0.f, 0.f, 0.f, 0.f}, 0, 0, 0);
            sc[0][tn] = __builtin_amdgcn_mfma_f32_16x16x32_bf16(kb1, qf[0][1], sc[0][tn], 0, 0, 0);
          }
        }
        __builtin_amdgcn_s_setprio(0);

        // per-group softmax (mask -> stats -> exp -> in-register pack)
        bf16x8 ap[2][2];
#pragma unroll
        for (int g = 0; g < 2; ++g) {
          if (g == 0 && !a0) continue;
          const int qbg = qb + g * 16;
          if (k0 + 63 > qbg) {           // causal mask, diagonal tiles only
            const int qg = qbg + lm;
#pragma unroll
            for (int tn = 0; tn < 4; ++tn) {
              const int kb_ = k0 + ((tn >> 1) << 5) + (quad << 3) + ((tn & 1) << 2);
#pragma unroll
              for (int r = 0; r < 4; ++r)
                if (kb_ + r > qg) sc[g][tn][r] = NEG_BIG;
            }
          }

          float mloc = fmaxf(fmaxf(hmax4(sc[g][0]), hmax4(sc[g][1])),
                             fmaxf(hmax4(sc[g][2]), hmax4(sc[g][3])));
          mloc = fmaxf(mloc, __shfl_xor(mloc, 16));
          mloc = fmaxf(mloc, __shfl_xor(mloc, 32));

          if (__any(mloc > m_i[g] + DEFER_THR)) {   // T13 defer-rescale
            const float mn = fmaxf(m_i[g], mloc);
            const float al = ex2(m_i[g] - mn);
            l_i[g] *= al; m_i[g] = mn;
            const float a0_ = __shfl(al, quad * 4 + 0, 16);
            const float a1_ = __shfl(al, quad * 4 + 1, 16);
            const float a2_ = __shfl(al, quad * 4 + 2, 16);
            const float a3_ = __shfl(al, quad * 4 + 3, 16);
#pragma unroll
            for (int tn = 0; tn < 4; ++tn) {
              o[g][tn][0] *= a0_; o[g][tn][1] *= a1_;
              o[g][tn][2] *= a2_; o[g][tn][3] *= a3_;
            }
          }

          float ls = 0.f;
#pragma unroll
          for (int tn = 0; tn < 4; ++tn) {
#pragma unroll
            for (int r = 0; r < 4; ++r) sc[g][tn][r] = ex2(sc[g][tn][r] - m_i[g]);
            ls += (sc[g][tn][0] + sc[g][tn][1]) + (sc[g][tn][2] + sc[g][tn][3]);
          }
          l_i[g] += ls;

          uint4 pw0, pw1;
          pw0.x = cvtpk(sc[g][0][0], sc[g][0][1]); pw0.y = cvtpk(sc[g][0][2], sc[g][0][3]);
          pw0.z = cvtpk(sc[g][1][0], sc[g][1][1]); pw0.w = cvtpk(sc[g][1][2], sc[g][1][3]);
          pw1.x = cvtpk(sc[g][2][0], sc[g][2][1]); pw1.y = cvtpk(sc[g][2][2], sc[g][2][3]);
          pw1.z = cvtpk(sc[g][3][0], sc[g][3][1]); pw1.w = cvtpk(sc[g][3][2], sc[g][3][3]);
          ap[g][0] = __builtin_bit_cast(bf16x8, pw0);
          ap[g][1] = __builtin_bit_cast(bf16x8, pw1);
        }

        // PV — V fragments read ONCE, feed both groups
        __builtin_amdgcn_s_setprio(1);
#pragma unroll
        for (int tn = 0; tn < 4; ++tn) {
          const int vrow = tn * 16 + lm;   // d index
          const int cv = quad ^ fv;
          bf16x8 vb0 = __builtin_bit_cast(bf16x8, Vs[vrow * 8 + cv]);
          bf16x8 vb1 = __builtin_bit_cast(bf16x8, Vs[vrow * 8 + (cv ^ 4)]);
          o[1][tn] = __builtin_amdgcn_mfma_f32_16x16x32_bf16(ap[1][0], vb0, o[1][tn], 0, 0, 0);
          o[1][tn] = __builtin_amdgcn_mfma_f32_16x16x32_bf16(ap[1][1], vb1, o[1][tn], 0, 0, 0);
          if (a0) {
            o[0][tn] = __builtin_amdgcn_mfma_f32_16x16x32_bf16(ap[0][0], vb0, o[0][tn], 0, 0, 0);
            o[0][tn] = __builtin_amdgcn_mfma_f32_16x16x32_bf16(ap[0][1], vb1, o[0][tn], 0, 0, 0);
          }
        }
        __builtin_amdgcn_s_setprio(0);
      }
      cur ^= 1;
    }

    // epilogue: reduce l across quads, normalize, stash O, coalesced store
    __syncthreads();
#pragma unroll
    for (int g = 0; g < 2; ++g) {
      uint16_t* const Ow = Os + (w * 32 + g * 16) * 72;
      float lr = l_i[g];
      lr += __shfl_xor(lr, 16);
      lr += __shfl_xor(lr, 32);
      const float inv = 1.f / lr;          // for q-row lm of group g
      const float i0 = __shfl(inv, quad * 4 + 0, 16);
      const float i1 = __shfl(inv, quad * 4 + 1, 16);
      const float i2 = __shfl(inv, quad * 4 + 2, 16);
      const float i3 = __shfl(inv, quad * 4 + 3, 16);
#pragma unroll
      for (int tn = 0; tn < 4; ++tn) {
        Ow[(quad * 4 + 0) * 72 + tn * 16 + lm] = f2bfu(o[g][tn][0] * i0);
        Ow[(quad * 4 + 1) * 72 + tn * 16 + lm] = f2bfu(o[g][tn][1] * i1);
        Ow[(quad * 4 + 2) * 72 + tn * 16 + lm] = f2bfu(o[g][tn][2] * i2);
        Ow[(quad * 4 + 3) * 72 + tn * 16 + lm] = f2bfu(o[g][tn][3] * i3);
      }
    }
    __syncthreads();

#pragma unroll
    for (int i = 0; i < 4; ++i) {
      const int idx = tid + i * 256;       // 0..1023 uint4
      const int row = idx >> 3, c = idx & 7;
      const uint4 v = *(const uint4*)(Os + row * 72 + c * 8);
      *(uint4*)(ctx + ((((size_t)b_ * S + q0 + row) * H + h_) << 6) + c * 8) = v;
    }
  }
}

} // namespace

extern "C" void kernel_launch(void* const* d_in, const int* in_sizes, int n_in,
                              void* d_out, int out_size, void* d_ws, size_t ws_size,
                              hipStream_t stream)
{
  const float* query = (const float*)d_in[0];
  const float* key_  = (const float*)d_in[1];
  const float* value = (const float*)d_in[2];
  const float* Wq    = (const float*)d_in[3];
  const float* bq    = (const float*)d_in[4];
  const float* Wk    = (const float*)d_in[5];
  const float* bk    = (const float*)d_in[6];
  const float* Wv    = (const float*)d_in[7];
  const float* bv    = (const float*)d_in[8];
  const float* Wo    = (const float*)d_in[9];
  const float* bo    = (const float*)d_in[10];
  // d_in[11]: causal mask — applied analytically in flash_mfma.

  const size_t qkv = (size_t)B * H * S * DK; // 8,388,608 elems (16.8MB bf16)
  const size_t DD  = (size_t)D * D;          // 1,048,576 elems (2MB bf16)
  bf16* slot0 = (bf16*)d_ws;        // q
  bf16* slot1 = slot0 + qkv;        // k
  bf16* slot2 = slot1 + qkv;        // vt (batched) / W scratch (fallback)
  bf16* slot3 = slot2 + qkv;        // vin ; later ctx
  bf16* slot4 = slot3 + qkv;        // batched only: Wq|Wk|Wv|Wo bf16 (8MB)
  bf16* dout0 = (bf16*)d_out;       // qin          (d_out scratch: fully
  bf16* dout1 = dout0 + qkv;        // kin           rewritten at the end)

  const int n8in = (int)(qkv / 8);          // 1048576
  const int n8w  = (int)(DD / 8);           // 131072
  const dim3 gproj(D / 128, M / 128);       // (8, 64)
  const dim3 gattn(B * H, 8);               // (64, 8)

  const size_t need = (4 * qkv + 4 * DD) * sizeof(bf16); // 75,497,472 B

  if (ws_size >= need) {
    // ---- batched path (4 launches) ----
    cvt_all<<<dim3((3 * n8in + 4 * n8w) / 256), 256, 0, stream>>>(
        query, key_, value, Wq, Wk, Wv, Wo, dout0, dout1, slot3, slot4);
    proj_qkv<<<dim3(D / 128, M / 128, 3), 256, 0, stream>>>(
        dout0, dout1, slot3, slot4, bq, bk, bv, slot0, slot1, slot2);
    flash_mfma<<<gattn, 256, 0, stream>>>(slot0, slot1, slot2, slot3);
    gemm_out<<<gproj, 512, 0, stream>>>(slot3, slot4 + 3 * DD, bo,
                                        (float*)d_out);
  } else {
    // ---- fallback: R10 sequence (9 launches) ----
    cvt3<<<dim3(n8in / 256, 3), 256, 0, stream>>>(query, key_, value,
                                                  dout0, dout1, slot3, n8in);
    cvt3<<<dim3(n8w / 256, 2), 256, 0, stream>>>(Wq, Wk, Wk,
                                                 slot2, slot2 + DD, slot2, n8w);
    gemm128<1><<<gproj, 256, 0, stream>>>(dout0, slot2, bq, slot0, D, D, QSCALE);
    gemm128<1><<<gproj, 256, 0, stream>>>(dout1, slot2 + DD, bk, slot1, D, D, 1.0f);
    cvt3<<<dim3(n8w / 256, 1), 256, 0, stream>>>(Wv, Wv, Wv,
                                                 dout0, dout0, dout0, n8w);
    gemm128<2><<<gproj, 256, 0, stream>>>(slot3, dout0, bv, slot2, D, D, 1.0f);
    flash_mfma<<<gattn, 256, 0, stream>>>(slot0, slot1, slot2, slot3);
    cvt3<<<dim3(n8w / 256, 1), 256, 0, stream>>>(Wo, Wo, Wo,
                                                 slot0, slot0, slot0, n8w);
    gemm128<0><<<gproj, 256, 0, stream>>>(slot3, slot0, bo, d_out, D, D, 1.0f);
  }
}

// Round 10
// 309.164 us; speedup vs baseline: 1.0752x; 1.0752x over previous
//
#include <hip/hip_runtime.h>
#include <hip/hip_bf16.h>
#include <cstdint>
#include <cstddef>

// MultiHeadAttention: B=4,S=2048,D=1024,H=16,DK=64, causal. fp32 in, fp32 out.
// Round 17:
//   - REVERT flash v6 (shared K/V reads halved occupancy 16->8 waves/CU;
//     83.8us + pathological outlier. Lesson x2: waves/CU is first-order).
//   - flash v7 = v5 inner code EXACTLY, but unpaired: one q-tile per block,
//     grid (64,16) = 1024 blocks -> 3 blocks/CU (LDS 50KB) = 24 waves/CU
//     (pairing grid-capped at 2 blocks/CU = 16). Longest-first scheduling
//     (qi = 15 - blockIdx.y): 32-iter blocks dispatch first, 2-iter blocks
//     pack the tail. Same per-CU work (68 tile-iters), 1.5x parallelism.
// Carried (verified): cvt_all; proj_qkv (74us, XCD remap, warm-L2); gemm_out
// (R14, 16 waves/CU); flash v5 machinery (key-permuted swapped QK^T,
// in-register softmax, T13, exp2-domain, dbuf K/V, XOR swizzle).
// Fragment layouts (HW-verified): A/B 16x16x32 [m|n=lane&15][k=quad*8+j];
// C/D col=lane&15, row=quad*4+reg.

namespace {

constexpr int B  = 4;
constexpr int S  = 2048;
constexpr int D  = 1024;
constexpr int H  = 16;
constexpr int DK = 64;
constexpr int M  = B * S;
constexpr float LOG2E     = 1.44269504088896f;
constexpr float QSCALE    = 0.125f * LOG2E;  // sm-scale folded with log2(e)
constexpr float NEG_BIG   = -1e30f;
constexpr float DEFER_THR = 8.0f;            // T13, log2 domain (p <= 2^8)

using bf16 = __hip_bfloat16;

typedef __attribute__((ext_vector_type(8))) __bf16 bf16x8;
typedef __attribute__((ext_vector_type(4))) float  f32x4;

__device__ __forceinline__ uint16_t f2bfu(float x) { // RNE fp32->bf16 bits
  uint32_t a = __builtin_bit_cast(uint32_t, x);
  return (uint16_t)((a + 0x7FFFu + ((a >> 16) & 1u)) >> 16);
}
__device__ __forceinline__ uint32_t pk2(float x, float y) {
  return (uint32_t)f2bfu(x) | ((uint32_t)f2bfu(y) << 16);
}
__device__ __forceinline__ float ex2(float x) { // 2^x
  float r; asm("v_exp_f32 %0, %1" : "=v"(r) : "v"(x)); return r;
}
__device__ __forceinline__ uint32_t cvtpk(float lo, float hi) { // {bf16(lo),bf16(hi)} RNE
  uint32_t r;
  asm("v_cvt_pk_bf16_f32 %0, %1, %2" : "=v"(r) : "v"(lo), "v"(hi));
  return r;
}
__device__ __forceinline__ float hmax4(f32x4 v) {
  return fmaxf(fmaxf(v[0], v[1]), fmaxf(v[2], v[3]));
}

// async 16B global -> LDS (wave-uniform LDS base + lane*16 implicit)
__device__ __forceinline__ void ldst16(const uint4* g, uint4* l) {
  __builtin_amdgcn_global_load_lds(
      (const __attribute__((address_space(1))) void*)g,
      (__attribute__((address_space(3))) void*)l, 16, 0, 0);
}

// XCD-bijective remap for 512-block (8x64) grids: orig = x + 8y.
__device__ __forceinline__ void xcd_remap(int& bx, int& by) {
  const int orig = blockIdx.x + (blockIdx.y << 3);
  bx = (orig >> 3) & 7;
  by = ((orig & 7) << 3) + (orig >> 6);
}

// ---------------------------------------------------------------------------
// cvt_all: all 7 fp32->bf16 conversions in one launch.
// ---------------------------------------------------------------------------
__global__ __launch_bounds__(256)
void cvt_all(const float* __restrict__ q, const float* __restrict__ k,
             const float* __restrict__ v, const float* __restrict__ wq,
             const float* __restrict__ wk, const float* __restrict__ wv,
             const float* __restrict__ wo, bf16* __restrict__ dq,
             bf16* __restrict__ dk, bf16* __restrict__ dv,
             bf16* __restrict__ dw)
{
  constexpr int N8IN = 1 << 20;            // qkv/8
  constexpr int N8W  = 1 << 17;            // D*D/8
  constexpr int T3   = 3 * N8IN;

  const int gi = blockIdx.x * 256 + threadIdx.x;
  const float* src; bf16* dst; int i;
  if (gi < T3) {
    const int z = gi >> 20; i = gi & (N8IN - 1);
    src = (z == 0) ? q : (z == 1) ? k : v;
    dst = (z == 0) ? dq : (z == 1) ? dk : dv;
  } else {
    const int j = gi - T3;
    const int z = j >> 17; i = j & (N8W - 1);
    src = (z == 0) ? wq : (z == 1) ? wk : (z == 2) ? wv : wo;
    dst = dw + ((size_t)z << 20);          // z * N8W * 8 elems
  }
  const float4 p = ((const float4*)src)[2 * i];
  const float4 r4 = ((const float4*)src)[2 * i + 1];
  uint4 r;
  r.x = pk2(p.x, p.y); r.y = pk2(p.z, p.w);
  r.z = pk2(r4.x, r4.y); r.w = pk2(r4.z, r4.w);
  ((uint4*)dst)[i] = r;
}

// ---------------------------------------------------------------------------
// fp32 -> bf16 bulk convert, up to 3 tensors per launch (fallback path only).
// ---------------------------------------------------------------------------
__global__ __launch_bounds__(256)
void cvt3(const float* __restrict__ a, const float* __restrict__ b,
          const float* __restrict__ c, bf16* __restrict__ x,
          bf16* __restrict__ y, bf16* __restrict__ z_, int n8)
{
  const int zz = blockIdx.y;
  const float* src = (zz == 0) ? a : (zz == 1) ? b : c;
  bf16*        dst = (zz == 0) ? x : (zz == 1) ? y : z_;
  const int i = blockIdx.x * 256 + threadIdx.x;
  if (i >= n8) return;
  const float4 p = ((const float4*)src)[2 * i];
  const float4 q = ((const float4*)src)[2 * i + 1];
  uint4 r;
  r.x = pk2(p.x, p.y); r.y = pk2(p.z, p.w);
  r.z = pk2(q.x, q.y); r.w = pk2(q.z, q.w);
  ((uint4*)dst)[i] = r;
}

// ---------------------------------------------------------------------------
// proj_qkv: the three input projections in one dispatch. blockIdx.z picks
// {Q,K,V}. A (bf16, pre-converted) and B (bf16 weights) both staged via
// global_load_lds. Single-buffer 32KB LDS, 2-barrier m97 loop, 4 blocks/CU.
// XCD-remapped within each z-slice.   [verified 74us, 49MB fetch]
// ---------------------------------------------------------------------------
__global__ __launch_bounds__(256, 4)
void proj_qkv(const bf16* __restrict__ Aq, const bf16* __restrict__ Ak,
              const bf16* __restrict__ Av, const bf16* __restrict__ Wall,
              const float* __restrict__ bq_, const float* __restrict__ bk_,
              const float* __restrict__ bv_, bf16* __restrict__ qo,
              bf16* __restrict__ ko, bf16* __restrict__ vto)
{
  __shared__ uint4 AsU[1024]; // 128 rows x 8 chunks (16KB)
  __shared__ uint4 BsU[1024];

  const int z = blockIdx.z;
  const bf16*  A    = (z == 0) ? Aq : (z == 1) ? Ak : Av;
  const bf16*  Wb   = Wall + (size_t)z * D * D;
  const float* bias = (z == 0) ? bq_ : (z == 1) ? bk_ : bv_;

  const int tid  = threadIdx.x;
  const int w    = tid >> 6;
  const int lane = tid & 63;
  const int lm   = lane & 15;
  const int quad = lane >> 4;
  const int wm   = (w >> 1) * 64;
  const int wn   = (w & 1) * 64;

  int bx, by; xcd_remap(bx, by);
  const int row0 = by * 128, col0 = bx * 128;
  constexpr int g8 = D >> 3; // 128 uint4 per row

  const uint4* Ag = (const uint4*)A + (size_t)row0 * g8;
  const uint4* Bg = (const uint4*)Wb + (size_t)col0 * g8;

  f32x4 acc[4][4] = {};

  for (int kt = 0; kt < D / 64; ++kt) {
    __syncthreads();
#pragma unroll
    for (int i = 0; i < 4; ++i) {
      const int chunk = i * 256 + w * 64 + lane; // 0..1023
      const int r = chunk >> 3, c = chunk & 7;
      ldst16(&Ag[(size_t)r * g8 + kt * 8 + c], &AsU[i * 256 + w * 64]);
      ldst16(&Bg[(size_t)r * g8 + kt * 8 + c], &BsU[i * 256 + w * 64]);
    }
    __syncthreads();
#pragma unroll
    for (int kk = 0; kk < 2; ++kk) {
      bf16x8 af[4], bfr[4];
#pragma unroll
      for (int tm = 0; tm < 4; ++tm)
        af[tm] = __builtin_bit_cast(bf16x8, AsU[(wm + tm * 16 + lm) * 8 + kk * 4 + quad]);
#pragma unroll
      for (int tn = 0; tn < 4; ++tn)
        bfr[tn] = __builtin_bit_cast(bf16x8, BsU[(wn + tn * 16 + lm) * 8 + kk * 4 + quad]);
#pragma unroll
      for (int tm = 0; tm < 4; ++tm)
#pragma unroll
        for (int tn = 0; tn < 4; ++tn)
          acc[tm][tn] = __builtin_amdgcn_mfma_f32_16x16x32_bf16(af[tm], bfr[tn], acc[tm][tn], 0, 0, 0);
    }
  }

  const float scale = (z == 0) ? QSCALE : 1.0f;
#pragma unroll
  for (int tm = 0; tm < 4; ++tm) {
#pragma unroll
    for (int tn = 0; tn < 4; ++tn) {
      const int col = col0 + wn + tn * 16 + lm;
      const float bv = bias[col];
      if (z == 2) {
        float vv[4];
#pragma unroll
        for (int r = 0; r < 4; ++r) vv[r] = acc[tm][tn][r] + bv;
        const int s0 = row0 + wm + tm * 16 + quad * 4;
        const int b_ = s0 >> 11, ss = s0 & (S - 1);
        const int h_ = col >> 6, dk = col & (DK - 1);
        uint2 st; st.x = pk2(vv[0], vv[1]); st.y = pk2(vv[2], vv[3]);
        *(uint2*)(vto + (((size_t)b_ * H + h_) * DK + dk) * S + ss) = st;
      } else {
        bf16* out = (z == 0) ? qo : ko;
#pragma unroll
        for (int r = 0; r < 4; ++r) {
          const int row = row0 + wm + tm * 16 + quad * 4 + r;
          const float v = (acc[tm][tn][r] + bv) * scale;
          const int b_ = row >> 11, s_ = row & (S - 1);
          const int h_ = col >> 6,  dk = col & (DK - 1);
          out[(((size_t)b_ * H + h_) * S + s_) * DK + dk] =
              __builtin_bit_cast(bf16, f2bfu(v));
        }
      }
    }
  }
}

// ---------------------------------------------------------------------------
// gemm_out: output projection. out = ctx@Wo^T + bo (fp32 [M,D] store).
// 512 thr = 8 waves (2Mx4N; wave owns 64x32 = 4x2 frags), 128x128 tile,
// BK=64, single-buffer 32KB LDS, XCD-remap. 16 waves/CU.   [R14]
// ---------------------------------------------------------------------------
__global__ __launch_bounds__(512)
void gemm_out(const bf16* __restrict__ A, const bf16* __restrict__ Wb,
              const float* __restrict__ bias, float* __restrict__ out)
{
  __shared__ uint4 AsU[1024]; // 128 rows x 8 chunks (16KB)
  __shared__ uint4 BsU[1024];

  const int tid  = threadIdx.x;
  const int w    = tid >> 6;          // 0..7
  const int lane = tid & 63;
  const int lm   = lane & 15;
  const int quad = lane >> 4;
  const int wm   = (w >> 2) * 64;     // 0 | 64
  const int wn   = (w & 3) * 32;      // 0 | 32 | 64 | 96

  int bx, by; xcd_remap(bx, by);
  const int row0 = by * 128, col0 = bx * 128;
  constexpr int g8 = D >> 3;

  const uint4* Ag = (const uint4*)A + (size_t)row0 * g8;
  const uint4* Bg = (const uint4*)Wb + (size_t)col0 * g8;

  f32x4 acc[4][2] = {};

  for (int kt = 0; kt < D / 64; ++kt) {
    __syncthreads();
#pragma unroll
    for (int i = 0; i < 2; ++i) {
      const int chunk = i * 512 + w * 64 + lane; // 0..1023
      const int r = chunk >> 3, c = chunk & 7;
      ldst16(&Ag[(size_t)r * g8 + kt * 8 + c], &AsU[i * 512 + w * 64]);
      ldst16(&Bg[(size_t)r * g8 + kt * 8 + c], &BsU[i * 512 + w * 64]);
    }
    __syncthreads();
#pragma unroll
    for (int kk = 0; kk < 2; ++kk) {
      bf16x8 af[4], bfr[2];
#pragma unroll
      for (int tm = 0; tm < 4; ++tm)
        af[tm] = __builtin_bit_cast(bf16x8, AsU[(wm + tm * 16 + lm) * 8 + kk * 4 + quad]);
#pragma unroll
      for (int tn = 0; tn < 2; ++tn)
        bfr[tn] = __builtin_bit_cast(bf16x8, BsU[(wn + tn * 16 + lm) * 8 + kk * 4 + quad]);
#pragma unroll
      for (int tm = 0; tm < 4; ++tm)
#pragma unroll
        for (int tn = 0; tn < 2; ++tn)
          acc[tm][tn] = __builtin_amdgcn_mfma_f32_16x16x32_bf16(af[tm], bfr[tn], acc[tm][tn], 0, 0, 0);
    }
  }

#pragma unroll
  for (int tm = 0; tm < 4; ++tm) {
#pragma unroll
    for (int tn = 0; tn < 2; ++tn) {
      const int col = col0 + wn + tn * 16 + lm;
      const float bv = bias[col];
#pragma unroll
      for (int r = 0; r < 4; ++r) {
        const int row = row0 + wm + tm * 16 + quad * 4 + r;
        out[(size_t)row * D + col] = acc[tm][tn][r] + bv;
      }
    }
  }
}

// ---------------------------------------------------------------------------
// gemm128 (fallback path only): dbuf 128x128, modes as before.
// ---------------------------------------------------------------------------
template <int MODE>
__global__ __launch_bounds__(256)
void gemm128(const bf16* __restrict__ A, const bf16* __restrict__ Wb,
             const float* __restrict__ bias, void* __restrict__ out,
             int N, int K, float scale)
{
  __shared__ uint4 AsU[2][1024];
  __shared__ uint4 BsU[2][1024];

  const int tid  = threadIdx.x;
  const int w    = tid >> 6;
  const int lane = tid & 63;
  const int lm   = lane & 15;
  const int quad = lane >> 4;
  const int wm   = (w >> 1) * 64;
  const int wn   = (w & 1) * 64;

  int bx, by; xcd_remap(bx, by);
  const int row0 = by * 128, col0 = bx * 128;
  const int g8 = K >> 3;

  const uint4* Ag = (const uint4*)A + (size_t)row0 * g8;
  const uint4* Bg = (const uint4*)Wb + (size_t)col0 * g8;

  f32x4 acc[4][4] = {};
  const int KT = K / 64;

#pragma unroll
  for (int i = 0; i < 4; ++i) {
    const int chunk = i * 256 + w * 64 + lane;
    const int r = chunk >> 3, c = chunk & 7;
    ldst16(&Ag[(size_t)r * g8 + c], &AsU[0][i * 256 + w * 64]);
    ldst16(&Bg[(size_t)r * g8 + c], &BsU[0][i * 256 + w * 64]);
  }

  int cur = 0;
  for (int kt = 0; kt < KT; ++kt) {
    __syncthreads();
    if (kt + 1 < KT) {
#pragma unroll
      for (int i = 0; i < 4; ++i) {
        const int chunk = i * 256 + w * 64 + lane;
        const int r = chunk >> 3, c = chunk & 7;
        ldst16(&Ag[(size_t)r * g8 + (kt + 1) * 8 + c], &AsU[cur ^ 1][i * 256 + w * 64]);
        ldst16(&Bg[(size_t)r * g8 + (kt + 1) * 8 + c], &BsU[cur ^ 1][i * 256 + w * 64]);
      }
    }
#pragma unroll
    for (int kk = 0; kk < 2; ++kk) {
      bf16x8 af[4], bfr[4];
#pragma unroll
      for (int tm = 0; tm < 4; ++tm)
        af[tm] = __builtin_bit_cast(bf16x8, AsU[cur][(wm + tm * 16 + lm) * 8 + kk * 4 + quad]);
#pragma unroll
      for (int tn = 0; tn < 4; ++tn)
        bfr[tn] = __builtin_bit_cast(bf16x8, BsU[cur][(wn + tn * 16 + lm) * 8 + kk * 4 + quad]);
#pragma unroll
      for (int tm = 0; tm < 4; ++tm)
#pragma unroll
        for (int tn = 0; tn < 4; ++tn)
          acc[tm][tn] = __builtin_amdgcn_mfma_f32_16x16x32_bf16(af[tm], bfr[tn], acc[tm][tn], 0, 0, 0);
    }
    cur ^= 1;
  }

#pragma unroll
  for (int tm = 0; tm < 4; ++tm) {
#pragma unroll
    for (int tn = 0; tn < 4; ++tn) {
      const int col = col0 + wn + tn * 16 + lm;
      const float bv = bias[col];
      if (MODE == 2) {
        float vv[4];
#pragma unroll
        for (int r = 0; r < 4; ++r) vv[r] = (acc[tm][tn][r] + bv) * scale;
        const int s0 = row0 + wm + tm * 16 + quad * 4;
        const int b_ = s0 >> 11, ss = s0 & (S - 1);
        const int h_ = col >> 6, dk = col & (DK - 1);
        uint2 st; st.x = pk2(vv[0], vv[1]); st.y = pk2(vv[2], vv[3]);
        *(uint2*)((bf16*)out + (((size_t)b_ * H + h_) * DK + dk) * S + ss) = st;
      } else {
#pragma unroll
        for (int r = 0; r < 4; ++r) {
          const int row = row0 + wm + tm * 16 + quad * 4 + r;
          const float v = (acc[tm][tn][r] + bv) * scale;
          if (MODE == 0) {
            ((float*)out)[(size_t)row * N + col] = v;
          } else {
            const int b_ = row >> 11, s_ = row & (S - 1);
            const int h_ = col >> 6,  dk = col & (DK - 1);
            ((bf16*)out)[(((size_t)b_ * H + h_) * S + s_) * DK + dk] =
                __builtin_bit_cast(bf16, f2bfu(v));
          }
        }
      }
    }
  }
}

// ---------------------------------------------------------------------------
// flash v7 (= v5 inner code, unpaired longest-first grid).
// Q,K: [B*H,S,DK] bf16 (Q pre-scaled by 0.125*log2e); Vt: [B*H,DK,S] bf16.
// Grid (B*H, 16), 512 thr = 8 waves; block handles q-tile qi = 15-blockIdx.y
// (longest first -> short blocks pack the tail); 3 blocks/CU (LDS 50KB) =
// 24 waves/CU (pairing was grid-capped at 16).
// Wave w owns q-rows qbase = q0 + w*16 + [0,16).
// Swapped QK^T key permutation: sc[tn][r] =
// S[k0+32(tn>>1)+8*quad+4(tn&1)+r][qbase+lm]; PV A-frags packed in-register
// (8 cvt_pk), no LDS round-trip. LDS swizzle f(row)=(row&7)^(((row>>3)&1)<<2).
// ---------------------------------------------------------------------------
__global__ __launch_bounds__(512)
void flash_mfma(const bf16* __restrict__ Q, const bf16* __restrict__ K,
                const bf16* __restrict__ Vt, bf16* __restrict__ ctx)
{
  __shared__ uint4 KsU[2][512];          // 2 x (64 keys x 64 dk) (16KB)
  __shared__ uint4 VtU[2][512];          // 2 x (64 d x 64 keys)  (16KB)
  __shared__ uint16_t Os[128 * 72];      // epilogue O staging (18KB)

  const int tid  = threadIdx.x;
  const int w    = tid >> 6;             // 0..7
  const int lane = tid & 63;
  const int lm   = lane & 15;
  const int quad = lane >> 4;
  const int bh   = blockIdx.x;           // 0..63
  const int qi   = 15 - blockIdx.y;      // longest-first
  const size_t base = (size_t)bh * S * DK;

  const uint4* Kg0 = (const uint4*)(K + base);
  const uint4* Vg0 = (const uint4*)(Vt + (size_t)bh * DK * S);

  // staging: LDS chunk (row r, col c) holds global chunk c ^ f(r),
  // f(r) = (r&7) ^ (((r>>3)&1)<<2); realized via pre-swizzled global source.
  const int rr  = w * 8 + (lane >> 3);                     // staged row
  const int csw = (lane & 7) ^ (lane >> 3) ^ ((w & 1) << 2); // source chunk
  const int fv  = (lm & 7) ^ (((lm >> 3) & 1) << 2);       // f for V rows tn*16+lm
  const int r0  = ((lm >> 2) << 3) | (lm & 3);             // K perm base row

  uint16_t* const Ow = Os + (w * 16) * 72;
  const int b_ = bh >> 4, h_ = bh & (H - 1);

  const int q0 = qi * 128;
  const int qbase = q0 + w * 16;

  bf16x8 qf0, qf1;
  {
    const bf16* qrow = Q + base + (size_t)(qbase + lm) * DK;
    qf0 = __builtin_bit_cast(bf16x8, *(const uint4*)(qrow + quad * 8));
    qf1 = __builtin_bit_cast(bf16x8, *(const uint4*)(qrow + 32 + quad * 8));
  }

  f32x4 o[4] = {};
  float m_i = NEG_BIG, l_i = 0.f;        // stats for q-row lm (lane-local)

  const int nt = 2 * qi + 2;

  // prologue: stage tile 0 into buf 0
  ldst16(&Kg0[(size_t)rr * 8 + csw],       &KsU[0][w * 64]);
  ldst16(&Vg0[(size_t)rr * (S / 8) + csw], &VtU[0][w * 64]);

  int cur = 0;
  for (int t = 0; t < nt; ++t) {
    __syncthreads();
    if (t + 1 < nt) {
      const int k1 = (t + 1) * 64;
      ldst16(&Kg0[(size_t)(k1 + rr) * 8 + csw],         &KsU[cur ^ 1][w * 64]);
      ldst16(&Vg0[(size_t)rr * (S / 8) + k1 / 8 + csw], &VtU[cur ^ 1][w * 64]);
    }
    const int k0 = t * 64;
    if (k0 <= qbase + 15) {              // wave-uniform causal skip
      const uint4* Ks = KsU[cur];
      const uint4* Vs = VtU[cur];

      // swapped QK^T: sc[tn][r] = S[k0 + 32(tn>>1)+8*quad+4(tn&1)+r][qbase+lm]
      f32x4 sc[4];
      __builtin_amdgcn_s_setprio(1);
#pragma unroll
      for (int tn = 0; tn < 4; ++tn) {
        const int row = r0 + ((tn & 1) << 2) + ((tn >> 1) << 5);
        const int fr  = (row & 7) ^ (((row >> 3) & 1) << 2);
        const int cb  = quad ^ fr;
        bf16x8 kb0 = __builtin_bit_cast(bf16x8, Ks[row * 8 + cb]);
        bf16x8 kb1 = __builtin_bit_cast(bf16x8, Ks[row * 8 + (cb ^ 4)]);
        sc[tn] = __builtin_amdgcn_mfma_f32_16x16x32_bf16(
                     kb0, qf0, f32x4{0.f, 0.f, 0.f, 0.f}, 0, 0, 0);
        sc[tn] = __builtin_amdgcn_mfma_f32_16x16x32_bf16(kb1, qf1, sc[tn], 0, 0, 0);
      }
      __builtin_amdgcn_s_setprio(0);

      // causal mask — diagonal tiles only
      if (k0 + 63 > qbase) {
        const int qg = qbase + lm;
#pragma unroll
        for (int tn = 0; tn < 4; ++tn) {
          const int kb_ = k0 + ((tn >> 1) << 5) + (quad << 3) + ((tn & 1) << 2);
#pragma unroll
          for (int r = 0; r < 4; ++r)
            if (kb_ + r > qg) sc[tn][r] = NEG_BIG;
        }
      }

      // per-row stats: lane holds 16 of row lm's keys; reduce across quads
      float mloc = fmaxf(fmaxf(hmax4(sc[0]), hmax4(sc[1])),
                         fmaxf(hmax4(sc[2]), hmax4(sc[3])));
      mloc = fmaxf(mloc, __shfl_xor(mloc, 16));
      mloc = fmaxf(mloc, __shfl_xor(mloc, 32));

      if (__any(mloc > m_i + DEFER_THR)) {   // T13 defer-rescale
        const float mn = fmaxf(m_i, mloc);
        const float al = ex2(m_i - mn);
        l_i *= al; m_i = mn;
        const float a0 = __shfl(al, quad * 4 + 0, 16);
        const float a1 = __shfl(al, quad * 4 + 1, 16);
        const float a2 = __shfl(al, quad * 4 + 2, 16);
        const float a3 = __shfl(al, quad * 4 + 3, 16);
#pragma unroll
        for (int tn = 0; tn < 4; ++tn) {
          o[tn][0] *= a0; o[tn][1] *= a1; o[tn][2] *= a2; o[tn][3] *= a3;
        }
      }

      float ls = 0.f;
#pragma unroll
      for (int tn = 0; tn < 4; ++tn) {
#pragma unroll
        for (int r = 0; r < 4; ++r) sc[tn][r] = ex2(sc[tn][r] - m_i);
        ls += (sc[tn][0] + sc[tn][1]) + (sc[tn][2] + sc[tn][3]);
      }
      l_i += ls;

      // P -> A-frags: pure in-register pack (keys already in frag order)
      uint4 pw0, pw1;
      pw0.x = cvtpk(sc[0][0], sc[0][1]); pw0.y = cvtpk(sc[0][2], sc[0][3]);
      pw0.z = cvtpk(sc[1][0], sc[1][1]); pw0.w = cvtpk(sc[1][2], sc[1][3]);
      pw1.x = cvtpk(sc[2][0], sc[2][1]); pw1.y = cvtpk(sc[2][2], sc[2][3]);
      pw1.z = cvtpk(sc[3][0], sc[3][1]); pw1.w = cvtpk(sc[3][2], sc[3][3]);
      const bf16x8 ap0 = __builtin_bit_cast(bf16x8, pw0);
      const bf16x8 ap1 = __builtin_bit_cast(bf16x8, pw1);

      __builtin_amdgcn_s_setprio(1);
#pragma unroll
      for (int tn = 0; tn < 4; ++tn) {
        const int vrow = tn * 16 + lm;   // d index
        const int cv = quad ^ fv;
        bf16x8 vb0 = __builtin_bit_cast(bf16x8, Vs[vrow * 8 + cv]);
        bf16x8 vb1 = __builtin_bit_cast(bf16x8, Vs[vrow * 8 + (cv ^ 4)]);
        o[tn] = __builtin_amdgcn_mfma_f32_16x16x32_bf16(ap0, vb0, o[tn], 0, 0, 0);
        o[tn] = __builtin_amdgcn_mfma_f32_16x16x32_bf16(ap1, vb1, o[tn], 0, 0, 0);
      }
      __builtin_amdgcn_s_setprio(0);
    }
    cur ^= 1;
  }

  // epilogue: reduce l across quads, normalize, stash O, coalesced store
  __syncthreads();
  {
    float lr = l_i;
    lr += __shfl_xor(lr, 16);
    lr += __shfl_xor(lr, 32);
    const float inv = 1.f / lr;          // for q-row lm
    const float i0 = __shfl(inv, quad * 4 + 0, 16);
    const float i1 = __shfl(inv, quad * 4 + 1, 16);
    const float i2 = __shfl(inv, quad * 4 + 2, 16);
    const float i3 = __shfl(inv, quad * 4 + 3, 16);
#pragma unroll
    for (int tn = 0; tn < 4; ++tn) {
      Ow[(quad * 4 + 0) * 72 + tn * 16 + lm] = f2bfu(o[tn][0] * i0);
      Ow[(quad * 4 + 1) * 72 + tn * 16 + lm] = f2bfu(o[tn][1] * i1);
      Ow[(quad * 4 + 2) * 72 + tn * 16 + lm] = f2bfu(o[tn][2] * i2);
      Ow[(quad * 4 + 3) * 72 + tn * 16 + lm] = f2bfu(o[tn][3] * i3);
    }
  }
  __syncthreads();

#pragma unroll
  for (int i = 0; i < 2; ++i) {
    const int idx = tid + i * 512;       // 0..1023 uint4
    const int row = idx >> 3, c = idx & 7;
    const uint4 v = *(const uint4*)(Os + row * 72 + c * 8);
    *(uint4*)(ctx + ((((size_t)b_ * S + q0 + row) * H + h_) << 6) + c * 8) = v;
  }
}

} // namespace

extern "C" void kernel_launch(void* const* d_in, const int* in_sizes, int n_in,
                              void* d_out, int out_size, void* d_ws, size_t ws_size,
                              hipStream_t stream)
{
  const float* query = (const float*)d_in[0];
  const float* key_  = (const float*)d_in[1];
  const float* value = (const float*)d_in[2];
  const float* Wq    = (const float*)d_in[3];
  const float* bq    = (const float*)d_in[4];
  const float* Wk    = (const float*)d_in[5];
  const float* bk    = (const float*)d_in[6];
  const float* Wv    = (const float*)d_in[7];
  const float* bv    = (const float*)d_in[8];
  const float* Wo    = (const float*)d_in[9];
  const float* bo    = (const float*)d_in[10];
  // d_in[11]: causal mask — applied analytically in flash_mfma.

  const size_t qkv = (size_t)B * H * S * DK; // 8,388,608 elems (16.8MB bf16)
  const size_t DD  = (size_t)D * D;          // 1,048,576 elems (2MB bf16)
  bf16* slot0 = (bf16*)d_ws;        // q
  bf16* slot1 = slot0 + qkv;        // k
  bf16* slot2 = slot1 + qkv;        // vt (batched) / W scratch (fallback)
  bf16* slot3 = slot2 + qkv;        // vin ; later ctx
  bf16* slot4 = slot3 + qkv;        // batched only: Wq|Wk|Wv|Wo bf16 (8MB)
  bf16* dout0 = (bf16*)d_out;       // qin          (d_out scratch: fully
  bf16* dout1 = dout0 + qkv;        // kin           rewritten at the end)

  const int n8in = (int)(qkv / 8);          // 1048576
  const int n8w  = (int)(DD / 8);           // 131072
  const dim3 gproj(D / 128, M / 128);       // (8, 64)
  const dim3 gattn(B * H, 16);              // (64, 16) — longest-first tiles

  const size_t need = (4 * qkv + 4 * DD) * sizeof(bf16); // 75,497,472 B

  if (ws_size >= need) {
    // ---- batched path (4 launches) ----
    cvt_all<<<dim3((3 * n8in + 4 * n8w) / 256), 256, 0, stream>>>(
        query, key_, value, Wq, Wk, Wv, Wo, dout0, dout1, slot3, slot4);
    proj_qkv<<<dim3(D / 128, M / 128, 3), 256, 0, stream>>>(
        dout0, dout1, slot3, slot4, bq, bk, bv, slot0, slot1, slot2);
    flash_mfma<<<gattn, 512, 0, stream>>>(slot0, slot1, slot2, slot3);
    gemm_out<<<gproj, 512, 0, stream>>>(slot3, slot4 + 3 * DD, bo,
                                        (float*)d_out);
  } else {
    // ---- fallback: R10-style sequence (9 launches) ----
    cvt3<<<dim3(n8in / 256, 3), 256, 0, stream>>>(query, key_, value,
                                                  dout0, dout1, slot3, n8in);
    cvt3<<<dim3(n8w / 256, 2), 256, 0, stream>>>(Wq, Wk, Wk,
                                                 slot2, slot2 + DD, slot2, n8w);
    gemm128<1><<<gproj, 256, 0, stream>>>(dout0, slot2, bq, slot0, D, D, QSCALE);
    gemm128<1><<<gproj, 256, 0, stream>>>(dout1, slot2 + DD, bk, slot1, D, D, 1.0f);
    cvt3<<<dim3(n8w / 256, 1), 256, 0, stream>>>(Wv, Wv, Wv,
                                                 dout0, dout0, dout0, n8w);
    gemm128<2><<<gproj, 256, 0, stream>>>(slot3, dout0, bv, slot2, D, D, 1.0f);
    flash_mfma<<<gattn, 512, 0, stream>>>(slot0, slot1, slot2, slot3);
    cvt3<<<dim3(n8w / 256, 1), 256, 0, stream>>>(Wo, Wo, Wo,
                                                 slot0, slot0, slot0, n8w);
    gemm128<0><<<gproj, 256, 0, stream>>>(slot3, slot0, bo, d_out, D, D, 1.0f);
  }
}